// Round 2
// baseline (755.145 us; speedup 1.0000x reference)
//
#include <hip/hip_runtime.h>
#include <hip/hip_bf16.h>

#define TOKENS 16384
#define EMB 4096
#define NEXP 64
#define BT 64
#define BK 64
#define NCHUNK (EMB / BK)  // 64

// One block: BT=64 tokens x all 64 experts. 256 threads; thread (tx,ty) owns
// tokens 4*ty..4*ty+3 and experts 4*tx..4*tx+3.
// Accumulation in fp64 (exact at this scale): top-2 index selection needs
// logits accurate to well below the min top-2/top-3 gap (~1e-5 over 16384
// tokens); sequential fp32 (err ~2.7e-6) flipped at least one token in R1.
// LDS tiles X[64][64] and W[64][64] fp32, double-buffered, float4-slot XOR
// swizzle slot(row,kq) = kq ^ (row>>2): X reads are 16-lane broadcasts
// (4 distinct addrs/wave), W reads 2-way (free per m136).
__global__ __launch_bounds__(256) void router_gemm_topk(
    const float* __restrict__ x, const float* __restrict__ W,
    const float* __restrict__ b, float* __restrict__ out)
{
    __shared__ float4 sX[2][BT][16];    // 32 KB
    __shared__ float4 sW[2][NEXP][16];  // 32 KB

    const int t  = threadIdx.x;
    const int tx = t & 15;   // expert group
    const int ty = t >> 4;   // token group (also staging row 0..15)
    const int t0 = blockIdx.x * BT;

    // bias folded into accumulator init: acc[i][j] belongs to expert 4*tx+j
    float4 bv = *reinterpret_cast<const float4*>(b + 4 * tx);
    double acc[4][4];
#pragma unroll
    for (int i = 0; i < 4; ++i) {
        acc[i][0] = (double)bv.x; acc[i][1] = (double)bv.y;
        acc[i][2] = (double)bv.z; acc[i][3] = (double)bv.w;
    }

    // staging: thread covers rows (16p + ty), float4 column tx, p = 0..3
    const float* gx = x + (size_t)(t0 + ty) * EMB + tx * 4;
    const float* gw = W + (size_t)ty * EMB + tx * 4;
    int slot[4];
#pragma unroll
    for (int p = 0; p < 4; ++p) slot[p] = tx ^ ((4 * p + (ty >> 2)) & 15);

    float4 rx[4], rw[4];
#pragma unroll
    for (int p = 0; p < 4; ++p) {
        rx[p] = *reinterpret_cast<const float4*>(gx + (size_t)(16 * p) * EMB);
        rw[p] = *reinterpret_cast<const float4*>(gw + (size_t)(16 * p) * EMB);
    }
#pragma unroll
    for (int p = 0; p < 4; ++p) {
        sX[0][16 * p + ty][slot[p]] = rx[p];
        sW[0][16 * p + ty][slot[p]] = rw[p];
    }
    __syncthreads();

    for (int kc = 0; kc < NCHUNK; ++kc) {
        const int buf = kc & 1;
        // prefetch next chunk into registers (latency hides under compute)
        if (kc + 1 < NCHUNK) {
            const int ko = (kc + 1) * BK;
#pragma unroll
            for (int p = 0; p < 4; ++p) {
                rx[p] = *reinterpret_cast<const float4*>(gx + (size_t)(16 * p) * EMB + ko);
                rw[p] = *reinterpret_cast<const float4*>(gw + (size_t)(16 * p) * EMB + ko);
            }
        }
        // compute on current buffer
        const float4* xrow = &sX[buf][4 * ty][0];
        const float4* wrow = &sW[buf][4 * tx][0];
#pragma unroll
        for (int kq = 0; kq < 16; ++kq) {
            const float4* xa = xrow + (kq ^ ty);   // row 4*ty+i at xa[16*i]
            const float4* wa = wrow + (kq ^ tx);
            float4 xq[4], wq[4];
#pragma unroll
            for (int i = 0; i < 4; ++i) xq[i] = xa[16 * i];
#pragma unroll
            for (int j = 0; j < 4; ++j) wq[j] = wa[16 * j];
            // e-outer: convert 8 floats -> 8 doubles, feed 16 dfma; keeps
            // live double count at 16 regs instead of 64
#pragma unroll
            for (int e = 0; e < 4; ++e) {
                double xe[4], we[4];
#pragma unroll
                for (int i = 0; i < 4; ++i)
                    xe[i] = (double)(reinterpret_cast<const float*>(&xq[i])[e]);
#pragma unroll
                for (int j = 0; j < 4; ++j)
                    we[j] = (double)(reinterpret_cast<const float*>(&wq[j])[e]);
#pragma unroll
                for (int i = 0; i < 4; ++i)
#pragma unroll
                    for (int j = 0; j < 4; ++j)
                        acc[i][j] = fma(xe[i], we[j], acc[i][j]);
            }
        }
        // write prefetched chunk into the other buffer (not read this iter)
        if (kc + 1 < NCHUNK) {
#pragma unroll
            for (int p = 0; p < 4; ++p) {
                sX[buf ^ 1][16 * p + ty][slot[p]] = rx[p];
                sW[buf ^ 1][16 * p + ty][slot[p]] = rw[p];
            }
        }
        __syncthreads();
    }

    // ---- epilogue: top-2 + softmax ----
    // gather logits into LDS, stride 65 to dodge bank conflicts on the scan
    float* lg = reinterpret_cast<float*>(&sX[0][0][0]);  // 64*65*4 = 16640 B
#pragma unroll
    for (int i = 0; i < 4; ++i)
#pragma unroll
        for (int j = 0; j < 4; ++j)
            lg[(4 * ty + i) * 65 + (4 * tx + j)] = (float)acc[i][j];
    __syncthreads();

    if (t < BT) {
        const float* row = lg + t * 65;
        float v1 = -3.4e38f; int i1 = 0;
        float v2 = -3.4e38f; int i2 = 0;
        for (int e = 0; e < NEXP; ++e) {
            float v = row[e];
            if (v > v1) { v2 = v1; i2 = i1; v1 = v; i1 = e; }
            else if (v > v2) { v2 = v; i2 = e; }
        }
        float e2  = expf(v2 - v1);          // <= 1, no overflow
        float inv = 1.0f / (1.0f + e2);
        int g = t0 + t;
        // output 0: topk_idx [TOKENS][2] (written as float values)
        out[2 * g]     = (float)i1;
        out[2 * g + 1] = (float)i2;
        // output 1: probs [TOKENS][2]
        out[2 * TOKENS + 2 * g]     = inv;
        out[2 * TOKENS + 2 * g + 1] = e2 * inv;
    }
}

extern "C" void kernel_launch(void* const* d_in, const int* in_sizes, int n_in,
                              void* d_out, int out_size, void* d_ws, size_t ws_size,
                              hipStream_t stream) {
    const float* x = (const float*)d_in[0];
    const float* W = (const float*)d_in[1];
    const float* b = (const float*)d_in[2];
    float* out = (float*)d_out;
    router_gemm_topk<<<dim3(TOKENS / BT), dim3(256), 0, stream>>>(x, W, b, out);
}

// Round 3
// 662.989 us; speedup vs baseline: 1.1390x; 1.1390x over previous
//
#include <hip/hip_runtime.h>
#include <hip/hip_bf16.h>

#define TOKENS 16384
#define EMB 4096
#define NEXP 64
#define BT 64
#define BK 64
#define NCHUNK (EMB / BK)  // 64

// One block: BT=64 tokens x all 64 experts. 256 threads; thread (tx,ty) owns
// tokens 4*ty..4*ty+3 and experts 4*tx..4*tx+3.
// Precision scheme: fp32 fma chains (exact products), TWO interleaved
// accumulator banks (even/odd k-quad) to halve partial-sum magnitudes,
// combined into fp64 accumulators every 64-k chunk. Total logit error
// ~1.2e-7 rms vs R1's sequential-fp32 1.6e-6 (which flipped top-2) and
// far below the min top-2/top-3 gap (~1e-5). fp64 work is 64 cvt+add per
// chunk (~5%) instead of 1024 dfma -> no 256-VGPR spill like R2.
// LDS tiles X[64][64] and W[64][64] fp32, double-buffered, float4-slot XOR
// swizzle slot(row,kq) = kq ^ (row>>2): X reads are 16-lane broadcasts,
// W reads 4-way shared.
__global__ __launch_bounds__(256) void router_gemm_topk(
    const float* __restrict__ x, const float* __restrict__ W,
    const float* __restrict__ b, float* __restrict__ out)
{
    __shared__ float4 sX[2][BT][16];    // 32 KB
    __shared__ float4 sW[2][NEXP][16];  // 32 KB

    const int t  = threadIdx.x;
    const int tx = t & 15;   // expert group
    const int ty = t >> 4;   // token group (also staging row 0..15)
    const int t0 = blockIdx.x * BT;

    // bias folded into fp64 accumulator init: acc[i][j] -> expert 4*tx+j
    float4 bv = *reinterpret_cast<const float4*>(b + 4 * tx);
    double acc64[4][4];
#pragma unroll
    for (int i = 0; i < 4; ++i) {
        acc64[i][0] = (double)bv.x; acc64[i][1] = (double)bv.y;
        acc64[i][2] = (double)bv.z; acc64[i][3] = (double)bv.w;
    }
    float acca[4][4], accb[4][4];

    // staging: thread covers rows (16p + ty), float4 column tx, p = 0..3
    const float* gx = x + (size_t)(t0 + ty) * EMB + tx * 4;
    const float* gw = W + (size_t)ty * EMB + tx * 4;
    int slot[4];
#pragma unroll
    for (int p = 0; p < 4; ++p) slot[p] = tx ^ ((4 * p + (ty >> 2)) & 15);

    float4 rx[4], rw[4];
#pragma unroll
    for (int p = 0; p < 4; ++p) {
        rx[p] = *reinterpret_cast<const float4*>(gx + (size_t)(16 * p) * EMB);
        rw[p] = *reinterpret_cast<const float4*>(gw + (size_t)(16 * p) * EMB);
    }
#pragma unroll
    for (int p = 0; p < 4; ++p) {
        sX[0][16 * p + ty][slot[p]] = rx[p];
        sW[0][16 * p + ty][slot[p]] = rw[p];
    }
    __syncthreads();

    for (int kc = 0; kc < NCHUNK; ++kc) {
        const int buf = kc & 1;
        // prefetch next chunk into registers (latency hides under compute)
        if (kc + 1 < NCHUNK) {
            const int ko = (kc + 1) * BK;
#pragma unroll
            for (int p = 0; p < 4; ++p) {
                rx[p] = *reinterpret_cast<const float4*>(gx + (size_t)(16 * p) * EMB + ko);
                rw[p] = *reinterpret_cast<const float4*>(gw + (size_t)(16 * p) * EMB + ko);
            }
        }
        // zero the fp32 chains for this chunk
#pragma unroll
        for (int i = 0; i < 4; ++i)
#pragma unroll
            for (int j = 0; j < 4; ++j) { acca[i][j] = 0.f; accb[i][j] = 0.f; }

        // compute on current buffer
        const float4* xrow = &sX[buf][4 * ty][0];
        const float4* wrow = &sW[buf][4 * tx][0];
#pragma unroll
        for (int kq = 0; kq < 16; ++kq) {
            const float4* xa = xrow + (kq ^ ty);   // row 4*ty+i at xa[16*i]
            const float4* wa = wrow + (kq ^ tx);
            float4 xq[4], wq[4];
#pragma unroll
            for (int i = 0; i < 4; ++i) xq[i] = xa[16 * i];
#pragma unroll
            for (int j = 0; j < 4; ++j) wq[j] = wa[16 * j];
            // compile-time bank select (kq is unrolled-constant)
#pragma unroll
            for (int i = 0; i < 4; ++i)
#pragma unroll
                for (int j = 0; j < 4; ++j) {
                    float s = (kq & 1) ? accb[i][j] : acca[i][j];
                    s = fmaf(xq[i].x, wq[j].x, s);
                    s = fmaf(xq[i].y, wq[j].y, s);
                    s = fmaf(xq[i].z, wq[j].z, s);
                    s = fmaf(xq[i].w, wq[j].w, s);
                    if (kq & 1) accb[i][j] = s; else acca[i][j] = s;
                }
        }
        // fold the two fp32 chains into the fp64 accumulators
#pragma unroll
        for (int i = 0; i < 4; ++i)
#pragma unroll
            for (int j = 0; j < 4; ++j)
                acc64[i][j] += (double)acca[i][j] + (double)accb[i][j];

        // write prefetched chunk into the other buffer (not read this iter)
        if (kc + 1 < NCHUNK) {
#pragma unroll
            for (int p = 0; p < 4; ++p) {
                sX[buf ^ 1][16 * p + ty][slot[p]] = rx[p];
                sW[buf ^ 1][16 * p + ty][slot[p]] = rw[p];
            }
        }
        __syncthreads();
    }

    // ---- epilogue: top-2 + softmax ----
    // gather fp32 logits into LDS, stride 65 to dodge bank conflicts
    float* lg = reinterpret_cast<float*>(&sX[0][0][0]);  // 64*65*4 = 16640 B
#pragma unroll
    for (int i = 0; i < 4; ++i)
#pragma unroll
        for (int j = 0; j < 4; ++j)
            lg[(4 * ty + i) * 65 + (4 * tx + j)] = (float)acc64[i][j];
    __syncthreads();

    if (t < BT) {
        const float* row = lg + t * 65;
        float v1 = -3.4e38f; int i1 = 0;
        float v2 = -3.4e38f; int i2 = 0;
        for (int e = 0; e < NEXP; ++e) {
            float v = row[e];
            if (v > v1) { v2 = v1; i2 = i1; v1 = v; i1 = e; }
            else if (v > v2) { v2 = v; i2 = e; }
        }
        float e2  = expf(v2 - v1);          // <= 1, no overflow
        float inv = 1.0f / (1.0f + e2);
        int g = t0 + t;
        // output 0: topk_idx [TOKENS][2] (written as float values)
        out[2 * g]     = (float)i1;
        out[2 * g + 1] = (float)i2;
        // output 1: probs [TOKENS][2]
        out[2 * TOKENS + 2 * g]     = inv;
        out[2 * TOKENS + 2 * g + 1] = e2 * inv;
    }
}

extern "C" void kernel_launch(void* const* d_in, const int* in_sizes, int n_in,
                              void* d_out, int out_size, void* d_ws, size_t ws_size,
                              hipStream_t stream) {
    const float* x = (const float*)d_in[0];
    const float* W = (const float*)d_in[1];
    const float* b = (const float*)d_in[2];
    float* out = (float*)d_out;
    router_gemm_topk<<<dim3(TOKENS / BT), dim3(256), 0, stream>>>(x, W, b, out);
}

// Round 4
// 182.117 us; speedup vs baseline: 4.1465x; 3.6404x over previous
//
#include <hip/hip_runtime.h>

#define TOKENS 16384
#define EMB 4096
#define NEXP 64
#define BT 64
#define BK 64
#define KSPLIT 2
#define KPER (EMB / KSPLIT)   // 2048
#define NCHUNK (KPER / BK)    // 32

// async global->LDS, 16B per lane; LDS dest is wave-uniform base + lane*16
__device__ __forceinline__ void gl_lds16(const float* g, void* lds) {
    __builtin_amdgcn_global_load_lds(
        (const __attribute__((address_space(1))) void*)g,
        (__attribute__((address_space(3))) void*)lds, 16, 0, 0);
}

// Kernel 1: partial GEMM. Block = 64 tokens x 64 experts x K-half (2048).
// grid (256, KSPLIT). 256 threads, thread (tx,ty) owns tokens 4ty..4ty+3,
// experts 4tx..4tx+3. LDS X[64][64] LINEAR (reads are 4-addr broadcasts ->
// conflict-free, immediate offsets), W[64][64] XOR-swizzled slot = kq ^
// (row>>2) realized by pre-swizzling the GLOBAL source (global_load_lds
// writes linearly; rule: linear dest + inverse-swz source + swz on read).
// Precision (R3-validated): dual fp32 fma banks (even/odd kq) folded into
// fp64 every 64-k chunk; fp32 partial write; cross-split fp32 add in k2.
// Total logit err ~1.5e-7 rms << min top-2/top-3 gap (~1e-5).
__global__ __launch_bounds__(256, 2) void router_partial(
    const float* __restrict__ x, const float* __restrict__ W,
    float* __restrict__ ws)
{
    __shared__ float4 sX[2][BT][16];    // 32 KB
    __shared__ float4 sW[2][NEXP][16];  // 32 KB

    const int t  = threadIdx.x;
    const int l  = t & 63;        // lane
    const int wv = t >> 6;        // wave 0..3
    const int tx = t & 15;        // expert group
    const int ty = t >> 4;        // token group 0..15
    const int t0 = blockIdx.x * BT;
    const int kb = blockIdx.y * KPER;

    // staging: wave wv, step p -> instr id q = 4p+wv stages LDS rows 4q..4q+3
    // (1024 B). lane l -> row 4q + (l>>4), slot l&15. X slot s holds k-quad s
    // (linear); W slot s holds k-quad s ^ q (XOR swizzle via source address).
    const float* gxs[4];
    const float* gws[4];
#pragma unroll
    for (int p = 0; p < 4; ++p) {
        const int q = 4 * p + wv;
        const int r = 4 * q + (l >> 4);
        gxs[p] = x + (size_t)(t0 + r) * EMB + kb + 4 * (l & 15);
        gws[p] = W + (size_t)r * EMB + kb + 4 * ((l & 15) ^ q);
    }

    double acc64[4][4];
#pragma unroll
    for (int i = 0; i < 4; ++i)
#pragma unroll
        for (int j = 0; j < 4; ++j) acc64[i][j] = 0.0;

    // prologue stage chunk 0 into buf 0
#pragma unroll
    for (int p = 0; p < 4; ++p) {
        const int q = 4 * p + wv;
        gl_lds16(gxs[p], &sX[0][4 * q][0]);
        gl_lds16(gws[p], &sW[0][4 * q][0]);
    }
    __syncthreads();

    for (int kc = 0; kc < NCHUNK; ++kc) {
        const int buf = kc & 1;
        if (kc + 1 < NCHUNK) {  // async prefetch next chunk into other buffer
            const int ko = (kc + 1) * BK;
#pragma unroll
            for (int p = 0; p < 4; ++p) {
                const int q = 4 * p + wv;
                gl_lds16(gxs[p] + ko, &sX[buf ^ 1][4 * q][0]);
                gl_lds16(gws[p] + ko, &sW[buf ^ 1][4 * q][0]);
            }
        }

        float a0[4][4], a1[4][4];
#pragma unroll
        for (int i = 0; i < 4; ++i)
#pragma unroll
            for (int j = 0; j < 4; ++j) { a0[i][j] = 0.f; a1[i][j] = 0.f; }

        const float4 (*X4)[16] = sX[buf];
        const float4 (*W4)[16] = sW[buf];
        // bounded unroll: caps in-flight ds_read dest regs (R3 spilled from
        // full-unroll hoisting: 16 iters x 8 b128 dests > 256 VGPR)
#pragma unroll 2
        for (int kq = 0; kq < 16; ++kq) {
            const int wslot = kq ^ tx;
            float4 xq[4], wq[4];
#pragma unroll
            for (int i = 0; i < 4; ++i) xq[i] = X4[4 * ty + i][kq];
#pragma unroll
            for (int j = 0; j < 4; ++j) wq[j] = W4[4 * tx + j][wslot];
#pragma unroll
            for (int i = 0; i < 4; ++i)
#pragma unroll
                for (int j = 0; j < 4; ++j) {
                    float s = (kq & 1) ? a1[i][j] : a0[i][j];  // static after unroll
                    s = fmaf(xq[i].x, wq[j].x, s);
                    s = fmaf(xq[i].y, wq[j].y, s);
                    s = fmaf(xq[i].z, wq[j].z, s);
                    s = fmaf(xq[i].w, wq[j].w, s);
                    if (kq & 1) a1[i][j] = s; else a0[i][j] = s;
                }
        }
        // fold fp32 chunk chains into fp64
#pragma unroll
        for (int i = 0; i < 4; ++i)
#pragma unroll
            for (int j = 0; j < 4; ++j)
                acc64[i][j] += (double)a0[i][j] + (double)a1[i][j];

        __syncthreads();  // drains vmcnt(0): prefetched chunk landed
    }

    // write fp32 partials: ws[(split*64 + e)*TOKENS + token], float4 over i
#pragma unroll
    for (int j = 0; j < 4; ++j) {
        float4 v;
        v.x = (float)acc64[0][j];
        v.y = (float)acc64[1][j];
        v.z = (float)acc64[2][j];
        v.w = (float)acc64[3][j];
        float* dst = ws + (size_t)(blockIdx.y * NEXP + 4 * tx + j) * TOKENS
                   + t0 + 4 * ty;
        *reinterpret_cast<float4*>(dst) = v;
    }
}

// Kernel 2: combine K-split partials + bias, top-2, softmax. 1 thread/token.
__global__ __launch_bounds__(64) void reduce_topk(
    const float* __restrict__ ws, const float* __restrict__ b,
    float* __restrict__ out)
{
    const int tok = blockIdx.x * 64 + threadIdx.x;
    float v1 = -3.4e38f, v2 = -3.4e38f;
    int i1 = 0, i2 = 0;
#pragma unroll 8
    for (int e = 0; e < NEXP; ++e) {
        float v = ws[(size_t)e * TOKENS + tok]
                + ws[(size_t)(NEXP + e) * TOKENS + tok] + b[e];
        if (v > v1) { v2 = v1; i2 = i1; v1 = v; i1 = e; }
        else if (v > v2) { v2 = v; i2 = e; }
    }
    float e2  = expf(v2 - v1);   // <= 1
    float inv = 1.0f / (1.0f + e2);
    out[2 * tok]     = (float)i1;
    out[2 * tok + 1] = (float)i2;
    out[2 * TOKENS + 2 * tok]     = inv;
    out[2 * TOKENS + 2 * tok + 1] = e2 * inv;
}

extern "C" void kernel_launch(void* const* d_in, const int* in_sizes, int n_in,
                              void* d_out, int out_size, void* d_ws, size_t ws_size,
                              hipStream_t stream) {
    const float* x = (const float*)d_in[0];
    const float* W = (const float*)d_in[1];
    const float* b = (const float*)d_in[2];
    float* out = (float*)d_out;
    float* ws  = (float*)d_ws;   // needs KSPLIT*NEXP*TOKENS*4 = 8.4 MB

    router_partial<<<dim3(TOKENS / BT, KSPLIT), dim3(256), 0, stream>>>(x, W, ws);
    reduce_topk<<<dim3(TOKENS / 64), dim3(64), 0, stream>>>(ws, b, out);
}